// Round 5
// baseline (603.146 us; speedup 1.0000x reference)
//
#include <hip/hip_runtime.h>

// CrossWinAttention on MI355X (gfx950). R12: single persistent kernel.
// R7-R11 established: k_attn wall (~52us clock-normalized) is invariant to
// occupancy (6/12/24 waves/CU), K source (global/LDS), explicit pipelining,
// wave staggering, and softmax structure — while OccupancyPercent says CUs
// are mostly EMPTY during the kernel. The untested overhead is BETWEEN
// kernels: 4 boundary drains + 3088 workgroup dispatches + launch gaps, over
// grids that are latency-starved (prep=16, out=256) or CP-heavy (lnproj=2304).
// R12 merges all four into one 512-block x 512-thread persistent kernel:
//   phase P (blocks 0-15) -> [grid barrier] -> phase L (2304 tasks, 2x256-thr
//   slots/block x 3 rounds) -> [grid barrier] -> phase A (1 (bl,h) task per
//   block, R11 attn body, 12 compute-waves/CU = R7 parity) -> [grid barrier]
//   -> phase O (blocks 0-255).
// Grid barriers: device-scope atomic counters in __device__ globals (zeroed at
// module load, self-resetting: last arriver of barrier i zeroes counter
// (i+2)%3 — safe because that counter's previous use fully completed), with
// __threadfence() release on ALL threads (Guideline 16: cross-XCD visibility).
// Residency proof (deadlock-free): 35840 B LDS -> 4 blk/CU LDS-wise; 8 waves
// -> 4 blk/CU wave-wise; __launch_bounds__(512,4) caps VGPR at 128 -> >=2
// blk/CU reg-wise => all 512 blocks co-resident.
// Carried: S^T trick, V^T key-swizzle, LN folded into GEMM epilogue, ones-MFMA
// softmax denominator (shuffle-free epilogue), scale*log2e folded into wq/bq,
// exp2-only softmax, hw bf16 cvt.

typedef unsigned short u16;
typedef __bf16 bf16x8 __attribute__((ext_vector_type(8)));
typedef __bf16 bf16x4 __attribute__((ext_vector_type(4)));
typedef float  f32x16 __attribute__((ext_vector_type(16)));
typedef unsigned short u16x8 __attribute__((ext_vector_type(8)));
typedef unsigned short u16x4 __attribute__((ext_vector_type(4)));

union U8 { u16x8 u; bf16x8 b; u16x4 h[2]; };

#if __has_builtin(__builtin_amdgcn_exp2f)
#define EXP2(x) __builtin_amdgcn_exp2f(x)
#else
#define EXP2(x) exp2f(x)
#endif

__device__ __forceinline__ f32x16 mfma_bf16(bf16x8 a, bf16x8 b, f32x16 c){
  return __builtin_amdgcn_mfma_f32_32x32x16_bf16(a, b, c, 0, 0, 0);
}

#define NBLK 512

// grid barrier: counters zero-initialized at module load; self-resetting so
// graph replays need no host-side reset. Last arriver of barrier i zeroes
// counter (i+2)%3 (its previous use is provably complete; next use is >=2
// barriers away).
__device__ int g_bar[3];

__device__ __forceinline__ void grid_sync(int idx){
  __threadfence();                       // all threads: release to device scope
  __syncthreads();
  if (threadIdx.x == 0){
    int prev = __hip_atomic_fetch_add(&g_bar[idx], 1, __ATOMIC_ACQ_REL,
                                      __HIP_MEMORY_SCOPE_AGENT);
    if (prev == NBLK - 1)
      __hip_atomic_store(&g_bar[(idx+2)%3], 0, __ATOMIC_RELAXED,
                         __HIP_MEMORY_SCOPE_AGENT);
    while (__hip_atomic_load(&g_bar[idx], __ATOMIC_ACQUIRE,
                             __HIP_MEMORY_SCOPE_AGENT) < NBLK)
      __builtin_amdgcn_s_sleep(2);
  }
  __syncthreads();
}

// 32x32x16 bf16 fragment conventions:
//  A: m=lane&31, k=(lane>>5)*8+j ; B: n=lane&31, k=(lane>>5)*8+j
//  C/D: col=lane&31, row=(reg&3)+8*(reg>>2)+4*(lane>>5)   [verified m74/m101]
// S^T = mfma(K, Q): col = q (fixed per lane), reg axis = keys. V^T stored with
// matching key swizzle so PV B-fragments are single 16B reads.
// Sum trick: mfma(P, ones, sl) -> sl rows align with O rows; normalize
// elementwise, no shuffles.

__global__ __launch_bounds__(512, 4) void k_fused(
    const float* __restrict__ q, const float* __restrict__ k,
    const float* __restrict__ v, const float* __restrict__ skip,
    const float* __restrict__ gq, const float* __restrict__ betq,
    const float* __restrict__ gk, const float* __restrict__ betk,
    const float* __restrict__ gv, const float* __restrict__ betv,
    const float* __restrict__ wq, const float* __restrict__ bq,
    const float* __restrict__ wk, const float* __restrict__ bk,
    const float* __restrict__ wv, const float* __restrict__ bv,
    const float* __restrict__ wp, const float* __restrict__ bp,
    float* __restrict__ out,
    u16* __restrict__ wqT, u16* __restrict__ wkT, u16* __restrict__ wvT,
    u16* __restrict__ wpT,
    float* __restrict__ bq2, float* __restrict__ bk2, float* __restrict__ bv2,
    float* __restrict__ uq2, float* __restrict__ uk2, float* __restrict__ uv2,
    u16* __restrict__ qh, u16* __restrict__ kh, u16* __restrict__ vh,
    u16* __restrict__ abar)
{
  __shared__ __align__(16) char smem[35840];   // per-phase overlay
  int tid = threadIdx.x;

  // ================================================= phase P: weight prep
  // 16 tasks = 4 weights x 4 col-chunks of 32; blocks 0-15, 512 thr.
  if (blockIdx.x < 16){
    float* wls  = (float*)smem;              // [128][33]
    float* gls  = (float*)(smem + 16896);    // 128
    float* bls  = (float*)(smem + 17408);    // 128
    float* redb = (float*)(smem + 17920);    // 128
    float* redu = (float*)(smem + 18432);    // 128
    const float ALPHA_Q = 0.17677669529663687f * 1.4426950408889634f; // DH^-0.5 * log2(e)
    int wsel = blockIdx.x >> 2, chunk = blockIdx.x & 3;
    const float *w, *bb, *g, *bet; u16* wT; float *b2, *u2; float alpha;
    if (wsel == 0){ w=wq; bb=bq; g=gq; bet=betq; wT=wqT; b2=bq2; u2=uq2; alpha=ALPHA_Q; }
    else if (wsel == 1){ w=wk; bb=bk; g=gk; bet=betk; wT=wkT; b2=bk2; u2=uk2; alpha=1.f; }
    else if (wsel == 2){ w=wv; bb=bv; g=gv; bet=betv; wT=wvT; b2=bv2; u2=uv2; alpha=1.f; }
    else { w=wp; bb=nullptr; g=nullptr; bet=nullptr; wT=wpT; b2=nullptr; u2=nullptr; alpha=1.f; }

    if (tid < 128){
      gls[tid] = g ? g[tid] : 1.f;
      bls[tid] = bet ? bet[tid] : 0.f;
    }
    const float4* w4 = (const float4*)w;
    #pragma unroll
    for (int i = 0; i < 2; i++){
      int idx = tid + i*512;               // 1024 float4s: 128 rows x 8
      int row = idx >> 3, f4c = idx & 7;
      float4 x = w4[row*32 + chunk*8 + f4c];
      wls[row*33 + f4c*4 + 0] = x.x;
      wls[row*33 + f4c*4 + 1] = x.y;
      wls[row*33 + f4c*4 + 2] = x.z;
      wls[row*33 + f4c*4 + 3] = x.w;
    }
    __syncthreads();
    if (tid < 128){
      int nl = tid >> 2, qp = tid & 3;
      float sb = 0.f, su = 0.f;
      alignas(16) __bf16 tmp[32];
      #pragma unroll
      for (int kk = 0; kk < 32; kk++){
        int k2 = qp*32 + kk;
        float wv_ = wls[k2*33 + nl];
        float gv_ = gls[k2];
        sb += bls[k2] * wv_;
        su += gv_ * wv_;
        tmp[kk] = (__bf16)(wv_ * gv_ * alpha);
      }
      int n = chunk*32 + nl;
      #pragma unroll
      for (int j = 0; j < 4; j++)
        *(bf16x8*)(wT + n*128 + qp*32 + j*8) = *(bf16x8*)&tmp[j*8];
      redb[tid] = sb; redu[tid] = su;
    }
    __syncthreads();
    if (tid < 128){
      int nl = tid >> 2, qp = tid & 3;
      if (qp == 0 && bb){
        int n = chunk*32 + nl;
        float s = bb[n] + redb[tid] + redb[tid+1] + redb[tid+2] + redb[tid+3];
        float u = redu[tid] + redu[tid+1] + redu[tid+2] + redu[tid+3];
        b2[n] = s * alpha;
        u2[n] = u * alpha;
      }
    }
  }
  grid_sync(0);

  // ================================================= phase L: LN + QKV proj
  // 2304 tasks; block runs 2 concurrent 256-thr slots x 3 rounds.
  // slot base = blockIdx.x + slot*512 (active if base < 768); task = base*3+r.
  {
    int slot = tid >> 8, t2 = tid & 255;
    int base = blockIdx.x + slot*512;
    char* sm = smem + slot*17920;
    u16* Abf   = (u16*)sm;                   // [64][136]
    float* s1s = (float*)(sm + 17408);       // 64 (rs)
    float* s2s = (float*)(sm + 17664);       // 64 (rm)
    #pragma unroll 1
    for (int r = 0; r < 3; ++r){
      bool act = base < 768;
      int task = base*3 + r;                 // which = r, tile t = base
      int which = r;
      int n = base % 6, bl = (base / 6) & 127;
      const float* src; const u16* wT; const float *b2, *u2; u16* dstb;
      if (which == 0){ src=q; wT=wqT; b2=bq2; u2=uq2; dstb=qh; }
      else if (which == 1){ src=k; wT=wkT; b2=bk2; u2=uk2; dstb=kh; }
      else { src=v; wT=wvT; b2=bv2; u2=uv2; dstb=vh; }
      (void)task;
      int b = bl >> 6, l = bl & 63;
      const float4* s4 = (const float4*)(src + (size_t)((b*6 + n)*64 + l)*64*128);
      int row = t2 >> 2, j = t2 & 3;
      float s1 = 0.f, s2 = 0.f;
      if (act){
        #pragma unroll
        for (int i = 0; i < 8; i++){
          float4 xv = s4[row*32 + i*4 + j];
          s1 += xv.x + xv.y + xv.z + xv.w;
          s2 += xv.x*xv.x + xv.y*xv.y + xv.z*xv.z + xv.w*xv.w;
          bf16x4 pk;
          pk[0] = (__bf16)xv.x; pk[1] = (__bf16)xv.y;
          pk[2] = (__bf16)xv.z; pk[3] = (__bf16)xv.w;
          *(bf16x4*)&Abf[row*136 + (i*4 + j)*4] = pk;
        }
      }
      s1 += __shfl_xor(s1, 1, 64); s1 += __shfl_xor(s1, 2, 64);
      s2 += __shfl_xor(s2, 1, 64); s2 += __shfl_xor(s2, 2, 64);
      if (act && j == 0){
        float m = s1 * (1.f/128.f);
        float rr = rsqrtf(s2 * (1.f/128.f) - m*m + 1e-5f);
        s1s[row] = rr;
        s2s[row] = rr * m;
      }
      __syncthreads();
      if (act){
        int wv2 = (tid >> 6) & 3, lane = tid & 63, lm = lane & 31, lh = lane >> 5;
        bf16x8 bfr[8];
        const u16* wrow = wT + (32*wv2 + lm)*128 + lh*8;
        #pragma unroll
        for (int ks = 0; ks < 8; ks++) bfr[ks] = *(const bf16x8*)(wrow + ks*16);
        f32x16 acc0, acc1;
        #pragma unroll
        for (int rr2 = 0; rr2 < 16; rr2++){ acc0[rr2]=0.f; acc1[rr2]=0.f; }
        #pragma unroll
        for (int ks = 0; ks < 8; ks++){
          bf16x8 a0 = *(const bf16x8*)&Abf[lm*136       + ks*16 + lh*8];
          bf16x8 a1 = *(const bf16x8*)&Abf[(32+lm)*136  + ks*16 + lh*8];
          acc0 = mfma_bf16(a0, bfr[ks], acc0);
          acc1 = mfma_bf16(a1, bfr[ks], acc1);
        }
        int col = 32*wv2 + lm;
        float u2c = u2[col], bc = b2[col];
        u16* dst = dstb + ((size_t)(bl*4 + wv2)*384 + n*64)*32 + lm;
        #pragma unroll
        for (int rr2 = 0; rr2 < 16; rr2++){
          int row0 = (rr2&3) + 8*(rr2>>2) + 4*lh;
          float y0 = s1s[row0]     * acc0[rr2] - s2s[row0]     * u2c + bc;
          float y1 = s1s[row0+32]  * acc1[rr2] - s2s[row0+32]  * u2c + bc;
          *(__bf16*)&dst[(size_t)row0*32]      = (__bf16)y0;
          *(__bf16*)&dst[(size_t)(32+row0)*32] = (__bf16)y1;
        }
      }
      __syncthreads();
    }
  }
  grid_sync(1);

  // ================================================= phase A: attention
  // one (bl,h) task per block; 6 compute waves (A/B dual chains), 8 staging.
  {
    u16* vts     = (u16*)smem;               // V^T [32][392]
    float* abar_s = (float*)(smem + 25088);  // [64][32] f32
    int bid2 = blockIdx.x;
    int h = bid2 & 3, bl = bid2 >> 2;
    const u16* qb = qh + (size_t)bid2 * 12288;
    const u16* kb = kh + (size_t)bid2 * 12288;
    const u16* vb = vh + (size_t)bid2 * 12288;
    int wave = tid >> 6, lane = tid & 63, lm = lane & 31, lh = lane >> 5;

    bf16x8 qfA0, qfA1, qfB0, qfB1;
    if (wave < 6){
      const u16* qbase = qb + (size_t)(wave*64 + lm)*32 + lh*8;
      qfA0 = *(const bf16x8*)(qbase);
      qfA1 = *(const bf16x8*)(qbase + 16);
      qfB0 = *(const bf16x8*)(qbase + 32*32);
      qfB1 = *(const bf16x8*)(qbase + 32*32 + 16);
    }
    // stage V transposed + key-swizzled (perm {0,2,1,3,4,6,5,7} on a-groups)
    for (int c = tid; c < 1536; c += 512){
      int key = c >> 2, part = c & 3;
      int u = key & 31, tt2 = key >> 5;
      int a = u >> 2;
      int anew = (a & 4) | ((a & 1) << 1) | ((a >> 1) & 1);
      int pos = tt2*32 + anew*4 + (u & 3);
      u16x8 vv = *(const u16x8*)(vb + key*32 + part*8);
      #pragma unroll
      for (int jj = 0; jj < 8; jj++) vts[(part*8 + jj)*392 + pos] = vv[jj];
    }
    for (int idx = tid; idx < 2048; idx += 512) abar_s[idx] = 0.f;
    __syncthreads();

    if (wave < 6){
      int n = wave;
      (void)n;
      const u16* vrow = &vts[lm*392 + 8*lh];
      const u16* krow = kb + lm*32 + lh*8;
      bf16x8 ones;
      #pragma unroll
      for (int j2 = 0; j2 < 8; j2++) ones[j2] = (__bf16)1.0f;
      f32x16 oA, oB, slA, slB;
      #pragma unroll
      for (int r2 = 0; r2 < 16; r2++){ oA[r2]=0.f; oB[r2]=0.f; slA[r2]=0.f; slB[r2]=0.f; }
      #pragma unroll
      for (int kt = 0; kt < 12; kt++){
        bf16x8 kf0 = *(const bf16x8*)(krow + kt*1024);
        bf16x8 kf1 = *(const bf16x8*)(krow + kt*1024 + 16);
        f32x16 sa, sb_;
        #pragma unroll
        for (int r2 = 0; r2 < 16; r2++){ sa[r2] = 0.f; sb_[r2] = 0.f; }
        __builtin_amdgcn_s_setprio(1);
        sa  = mfma_bf16(kf0, qfA0, sa);
        sb_ = mfma_bf16(kf0, qfB0, sb_);
        sa  = mfma_bf16(kf1, qfA1, sa);
        sb_ = mfma_bf16(kf1, qfB1, sb_);
        __builtin_amdgcn_s_setprio(0);
        U8 v0, v1;
        v0.u = *(const u16x8*)(vrow + kt*32);
        v1.u = *(const u16x8*)(vrow + kt*32 + 16);
        U8 pA0, pA1, pB0, pB1;
        #pragma unroll
        for (int r2 = 0; r2 < 8; r2++){
          pA0.b[r2] = (__bf16)EXP2(sa[r2]);
          pA1.b[r2] = (__bf16)EXP2(sa[r2+8]);
          pB0.b[r2] = (__bf16)EXP2(sb_[r2]);
          pB1.b[r2] = (__bf16)EXP2(sb_[r2+8]);
        }
        __builtin_amdgcn_s_setprio(1);
        oA  = mfma_bf16(pA0.b, v0.b, oA);
        oB  = mfma_bf16(pB0.b, v0.b, oB);
        slA = mfma_bf16(pA0.b, ones, slA);
        slB = mfma_bf16(pB0.b, ones, slB);
        oA  = mfma_bf16(pA1.b, v1.b, oA);
        oB  = mfma_bf16(pB1.b, v1.b, oB);
        slA = mfma_bf16(pA1.b, ones, slA);
        slB = mfma_bf16(pB1.b, ones, slB);
        __builtin_amdgcn_s_setprio(0);
      }
      #pragma unroll
      for (int r2 = 0; r2 < 16; r2++){
        int q_l = (r2&3) + 8*(r2>>2) + 4*lh;
        float ia = (1.f/6.f) * __builtin_amdgcn_rcpf(slA[r2]);
        float ib = (1.f/6.f) * __builtin_amdgcn_rcpf(slB[r2]);
        atomicAdd(&abar_s[q_l*32 + lm], oA[r2]*ia);
        atomicAdd(&abar_s[(32 + q_l)*32 + lm], oB[r2]*ib);
      }
    }
    __syncthreads();
    u16* ob = abar + (size_t)(bl*64)*128 + h*32;
    for (int idx = tid; idx < 2048; idx += 512){
      int w12 = idx >> 5, dh = idx & 31;
      *(__bf16*)&ob[(size_t)w12*128 + dh] = (__bf16)abar_s[idx];
    }
  }
  grid_sync(2);

  // ================================================= phase O: projection+skip
  // blocks 0-255: 32 rows each; GEMM on first 4 waves.
  if (blockIdx.x < 256){
    u16* Als = (u16*)smem;                   // [32][136]
    int R0 = blockIdx.x * 32;
    {
      int c = tid;                           // exactly 512 chunks
      int row = c >> 4, part = c & 15;
      *(u16x8*)&Als[row*136 + part*8] =
          *(const u16x8*)(abar + (size_t)(R0+row)*128 + part*8);
    }
    __syncthreads();
    if (tid < 256){
      int wave = tid >> 6, lane = tid & 63, lm = lane & 31, lh = lane >> 5;
      bf16x8 bfr[8];
      const u16* wrow = wpT + (32*wave + lm)*128 + lh*8;
      #pragma unroll
      for (int ks = 0; ks < 8; ks++) bfr[ks] = *(const bf16x8*)(wrow + ks*16);
      f32x16 acc;
      #pragma unroll
      for (int r2 = 0; r2 < 16; r2++) acc[r2] = 0.f;
      #pragma unroll
      for (int ks = 0; ks < 8; ks++){
        bf16x8 a0 = *(const bf16x8*)&Als[lm*136 + ks*16 + lh*8];
        acc = mfma_bf16(a0, bfr[ks], acc);
      }
      float bias = bp[32*wave + lm];
      #pragma unroll
      for (int r2 = 0; r2 < 16; r2++){
        int row0 = (r2&3) + 8*(r2>>2) + 4*lh;
        size_t f0 = (size_t)(R0 + row0)*128 + 32*wave + lm;
        out[f0] = acc[r2] + bias + skip[f0];
      }
    }
  }
}

// ---------------------------------------------------------------- launch
extern "C" void kernel_launch(void* const* d_in, const int* in_sizes, int n_in,
                              void* d_out, int out_size, void* d_ws, size_t ws_size,
                              hipStream_t stream)
{
  const float* q    = (const float*)d_in[0];
  const float* k    = (const float*)d_in[1];
  const float* v    = (const float*)d_in[2];
  const float* skip = (const float*)d_in[3];
  const float* gq   = (const float*)d_in[4];
  const float* betq = (const float*)d_in[5];
  const float* gk   = (const float*)d_in[6];
  const float* betk = (const float*)d_in[7];
  const float* gv   = (const float*)d_in[8];
  const float* betv = (const float*)d_in[9];
  const float* wq   = (const float*)d_in[10];
  const float* bq   = (const float*)d_in[11];
  const float* wk   = (const float*)d_in[12];
  const float* bk   = (const float*)d_in[13];
  const float* wv   = (const float*)d_in[14];
  const float* bv   = (const float*)d_in[15];
  const float* wp   = (const float*)d_in[16];
  const float* bp   = (const float*)d_in[17];
  float* out = (float*)d_out;

  char* ws = (char*)d_ws;
  u16* wqT = (u16*)ws;                 // 16384 u16 each
  u16* wkT = wqT + 16384;
  u16* wvT = wkT + 16384;
  u16* wpT = wvT + 16384;
  float* bq2 = (float*)(ws + 131072);  // 128 f32 each
  float* bk2 = bq2 + 128;
  float* bv2 = bk2 + 128;
  float* uq2 = bv2 + 128;
  float* uk2 = uq2 + 128;
  float* uv2 = uk2 + 128;
  u16* qh = (u16*)(ws + 134144);       // [128][4][384][32] bf16 = 12.58 MB each
  u16* kh = qh + 6291456;
  u16* vh = kh + 6291456;
  u16* abar = vh + 6291456;            // [8192][128] bf16 = 2 MB

  k_fused<<<NBLK, 512, 0, stream>>>(
      q, k, v, skip, gq, betq, gk, betk, gv, betv,
      wq, bq, wk, bk, wv, bv, wp, bp, out,
      wqT, wkT, wvT, wpT, bq2, bk2, bv2, uq2, uk2, uv2,
      qh, kh, vh, abar);
}

// Round 7
// 219.136 us; speedup vs baseline: 2.7524x; 2.7524x over previous
//
#include <hip/hip_runtime.h>

// CrossWinAttention on MI355X (gfx950), bf16 MFMA pipeline. R13b (compile fix
// of R13: anonymous-union-in-cast replaced by typed-pointer bf16 store):
//  - R12 persistent-fusion postmortem: phase-union body wrecked regalloc
//    (WRITE 188MB scratch, 503us). Reverted to R11's 4-kernel structure.
//  - k_attn concurrency model (from R7/R8/R11 data): sustained HBM/L3 fetch
//    rate scales with resident waves (R8: 2x waves -> 775 GB/s vs 400), and
//    wall = FETCH / rate. Little's law: 12 waves/CU x ~2x16B in flight /
//    ~250ns x 256 CU ~= 390 GB/s = measured. So: more waves, same bytes.
//    R13 splits n across 2 blocks: grid 1024 x 192 thr (3 waves, n=3g..3g+2),
//    LDS 33.3KB -> 4 blocks/CU = 12 waves/CU, per-wave code identical to R11
//    (VGPR ~72, no launch_bounds cap -> no spills). Each half writes an f32
//    partial abar buffer; k_out sums the two (same f32-accumulate precision
//    class as R11's 6-way LDS atomic sum).
//  - k_lnproj: C-tile now staged through LDS -> u16x8 fully-coalesced global
//    stores (was: 32 scalar 2B scatter stores per thread).
//  - k_prep: R11 version (grid 16).
//  - Carried: S^T trick, V^T key-swizzle, LN folded into GEMM epilogue,
//    ones-MFMA softmax denominator (shuffle-free epilogue), scale*log2e
//    folded into wq/bq (exp2-only softmax), hw bf16 cvt.

typedef unsigned short u16;
typedef __bf16 bf16x8 __attribute__((ext_vector_type(8)));
typedef __bf16 bf16x4 __attribute__((ext_vector_type(4)));
typedef float  f32x16 __attribute__((ext_vector_type(16)));
typedef unsigned short u16x8 __attribute__((ext_vector_type(8)));
typedef unsigned short u16x4 __attribute__((ext_vector_type(4)));

union U8 { u16x8 u; bf16x8 b; u16x4 h[2]; };

#if __has_builtin(__builtin_amdgcn_exp2f)
#define EXP2(x) __builtin_amdgcn_exp2f(x)
#else
#define EXP2(x) exp2f(x)
#endif

__device__ __forceinline__ f32x16 mfma_bf16(bf16x8 a, bf16x8 b, f32x16 c){
  return __builtin_amdgcn_mfma_f32_32x32x16_bf16(a, b, c, 0, 0, 0);
}

// 32x32x16 bf16 fragment conventions:
//  A: m=lane&31, k=(lane>>5)*8+j ; B: n=lane&31, k=(lane>>5)*8+j
//  C/D: col=lane&31, row=(reg&3)+8*(reg>>2)+4*(lane>>5)   [verified m74/m101]
// S^T = mfma(K, Q): col = q (fixed per lane), reg axis = keys. V^T stored with
// matching key swizzle so PV B-fragments are single 16B reads.
// Sum trick: mfma(P, ones, sl) -> sl rows align with O rows; normalize
// elementwise, no shuffles.

// ---------------------------------------------------------------- k_prep
// grid 16 = 4 weights x 4 col-chunks; 512 thr.
__global__ __launch_bounds__(512) void k_prep(
    const float* __restrict__ wq, const float* __restrict__ bq,
    const float* __restrict__ gq, const float* __restrict__ betq,
    const float* __restrict__ wk, const float* __restrict__ bk,
    const float* __restrict__ gk, const float* __restrict__ betk,
    const float* __restrict__ wv, const float* __restrict__ bv,
    const float* __restrict__ gv, const float* __restrict__ betv,
    const float* __restrict__ wp,
    u16* __restrict__ wqT, u16* __restrict__ wkT, u16* __restrict__ wvT, u16* __restrict__ wpT,
    float* __restrict__ bq2, float* __restrict__ bk2, float* __restrict__ bv2,
    float* __restrict__ uq2, float* __restrict__ uk2, float* __restrict__ uv2)
{
  __shared__ float wls[128*33];
  __shared__ float gls[128], bls[128];
  __shared__ float redb[128], redu[128];
  const float ALPHA_Q = 0.17677669529663687f * 1.4426950408889634f; // DH^-0.5 * log2(e)
  int bid = blockIdx.x, tid = threadIdx.x;
  int wsel = bid >> 2, chunk = bid & 3;
  const float *w, *bb, *g, *bet; u16* wT; float *b2, *u2; float alpha;
  if (wsel == 0){ w=wq; bb=bq; g=gq; bet=betq; wT=wqT; b2=bq2; u2=uq2; alpha=ALPHA_Q; }
  else if (wsel == 1){ w=wk; bb=bk; g=gk; bet=betk; wT=wkT; b2=bk2; u2=uk2; alpha=1.f; }
  else if (wsel == 2){ w=wv; bb=bv; g=gv; bet=betv; wT=wvT; b2=bv2; u2=uv2; alpha=1.f; }
  else { w=wp; bb=nullptr; g=nullptr; bet=nullptr; wT=wpT; b2=nullptr; u2=nullptr; alpha=1.f; }

  if (tid < 128){
    gls[tid] = g ? g[tid] : 1.f;
    bls[tid] = bet ? bet[tid] : 0.f;
  }
  const float4* w4 = (const float4*)w;
  #pragma unroll
  for (int i = 0; i < 2; i++){
    int idx = tid + i*512;
    int row = idx >> 3, f4c = idx & 7;
    float4 x = w4[row*32 + chunk*8 + f4c];
    wls[row*33 + f4c*4 + 0] = x.x;
    wls[row*33 + f4c*4 + 1] = x.y;
    wls[row*33 + f4c*4 + 2] = x.z;
    wls[row*33 + f4c*4 + 3] = x.w;
  }
  __syncthreads();
  if (tid < 128){
    int nl = tid >> 2, qp = tid & 3;
    float sb = 0.f, su = 0.f;
    alignas(16) __bf16 tmp[32];
    #pragma unroll
    for (int kk = 0; kk < 32; kk++){
      int k2 = qp*32 + kk;
      float wv_ = wls[k2*33 + nl];
      float gv_ = gls[k2];
      sb += bls[k2] * wv_;
      su += gv_ * wv_;
      tmp[kk] = (__bf16)(wv_ * gv_ * alpha);
    }
    int n = chunk*32 + nl;
    #pragma unroll
    for (int j = 0; j < 4; j++)
      *(bf16x8*)(wT + n*128 + qp*32 + j*8) = *(bf16x8*)&tmp[j*8];
    redb[tid] = sb; redu[tid] = su;
  }
  __syncthreads();
  if (tid < 128){
    int nl = tid >> 2, qp = tid & 3;
    if (qp == 0 && bb){
      int n = chunk*32 + nl;
      float s = bb[n] + redb[tid] + redb[tid+1] + redb[tid+2] + redb[tid+3];
      float u = redu[tid] + redu[tid+1] + redu[tid+2] + redu[tid+3];
      b2[n] = s * alpha;
      u2[n] = u * alpha;
    }
  }
}

// ---------------------------------------------------------------- k_lnproj
// grid 2304 = 128 (b,l) * 6 (n) * 3 (q/k/v); 256 thr (4 waves).
// Raw-x bf16 GEMM; LN in epilogue; C staged via LDS for coalesced stores.
__global__ __launch_bounds__(256) void k_lnproj(
    const float* __restrict__ qg, const float* __restrict__ kg, const float* __restrict__ vg,
    const u16* __restrict__ wqT, const u16* __restrict__ wkT, const u16* __restrict__ wvT,
    const float* __restrict__ bq2, const float* __restrict__ bk2, const float* __restrict__ bv2,
    const float* __restrict__ uq2, const float* __restrict__ uk2, const float* __restrict__ uv2,
    u16* __restrict__ qh, u16* __restrict__ kh, u16* __restrict__ vh)
{
  __shared__ alignas(16) u16 Abf[64*136];
  __shared__ float s1s[64], s2s[64];     // rs / rm
  int bid = blockIdx.x, tid = threadIdx.x;
  int which = bid % 3;
  int t = bid / 3;
  int n = t % 6, bl = t / 6;
  const float* src; const u16* wT; const float *b2, *u2; u16* dstb;
  if (which == 0){ src=qg; wT=wqT; b2=bq2; u2=uq2; dstb=qh; }
  else if (which == 1){ src=kg; wT=wkT; b2=bk2; u2=uk2; dstb=kh; }
  else { src=vg; wT=wvT; b2=bv2; u2=uv2; dstb=vh; }
  int b = bl >> 6, l = bl & 63;
  const float4* s4 = (const float4*)(src + (size_t)((b*6 + n)*64 + l)*64*128);
  int row = tid >> 2, j = tid & 3;
  float s1 = 0.f, s2 = 0.f;
  #pragma unroll
  for (int i = 0; i < 8; i++){
    float4 xv = s4[row*32 + i*4 + j];
    s1 += xv.x + xv.y + xv.z + xv.w;
    s2 += xv.x*xv.x + xv.y*xv.y + xv.z*xv.z + xv.w*xv.w;
    bf16x4 pk;
    pk[0] = (__bf16)xv.x; pk[1] = (__bf16)xv.y;
    pk[2] = (__bf16)xv.z; pk[3] = (__bf16)xv.w;
    *(bf16x4*)&Abf[row*136 + (i*4 + j)*4] = pk;
  }
  s1 += __shfl_xor(s1, 1, 64); s1 += __shfl_xor(s1, 2, 64);
  s2 += __shfl_xor(s2, 1, 64); s2 += __shfl_xor(s2, 2, 64);
  if (j == 0){
    float m = s1 * (1.f/128.f);
    float r = rsqrtf(s2 * (1.f/128.f) - m*m + 1e-5f);
    s1s[row] = r;          // rs
    s2s[row] = r * m;      // rm
  }
  __syncthreads();
  int wave = tid >> 6, lane = tid & 63, lm = lane & 31, lh = lane >> 5;
  bf16x8 bfr[8];
  const u16* wrow = wT + (32*wave + lm)*128 + lh*8;
  #pragma unroll
  for (int ks = 0; ks < 8; ks++) bfr[ks] = *(const bf16x8*)(wrow + ks*16);
  f32x16 acc0, acc1;
  #pragma unroll
  for (int r = 0; r < 16; r++){ acc0[r]=0.f; acc1[r]=0.f; }
  #pragma unroll
  for (int ks = 0; ks < 8; ks++){
    bf16x8 a0 = *(const bf16x8*)&Abf[lm*136       + ks*16 + lh*8];
    bf16x8 a1 = *(const bf16x8*)&Abf[(32+lm)*136  + ks*16 + lh*8];
    acc0 = mfma_bf16(a0, bfr[ks], acc0);
    acc1 = mfma_bf16(a1, bfr[ks], acc1);
  }
  int col = 32*wave + lm;
  float u2c = u2[col], bc = b2[col];
  __syncthreads();                       // all waves done READING Abf
  #pragma unroll
  for (int r = 0; r < 16; r++){
    int row0 = (r&3) + 8*(r>>2) + 4*lh;
    float y0 = s1s[row0]     * acc0[r] - s2s[row0]     * u2c + bc;
    float y1 = s1s[row0+32]  * acc1[r] - s2s[row0+32]  * u2c + bc;
    *(__bf16*)&Abf[row0*136 + col]      = (__bf16)y0;
    *(__bf16*)&Abf[(32+row0)*136 + col] = (__bf16)y1;
  }
  __syncthreads();
  // coalesced store: 1024 u16x8 chunks = 4 colgroups x 64 rows x 4 parts
  #pragma unroll
  for (int i = 0; i < 4; i++){
    int c = tid + i*256;
    int grp = c >> 8, rw = (c >> 2) & 63, part = c & 3;
    u16x8 val = *(const u16x8*)&Abf[rw*136 + grp*32 + part*8];
    *(u16x8*)(dstb + ((size_t)(bl*4 + grp)*384 + n*64 + rw)*32 + part*8) = val;
  }
}

// ---------------------------------------------------------------- k_attn
// grid 1024 = (bl,h) x 2 n-halves; 192 thr = 3 waves; wave = n within half.
// LDS 33.3 KB -> 4 blocks/CU = 12 waves/CU (the concurrency lever), per-wave
// body identical to R11. f32 partial output per half; k_out sums.
__global__ __launch_bounds__(192) void k_attn(
    const u16* __restrict__ qh, const u16* __restrict__ kh, const u16* __restrict__ vh,
    float* __restrict__ abp0, float* __restrict__ abp1)
{
  __shared__ alignas(16) u16 vts[32*392];   // V^T [dh][swizzled key], stride 392
  __shared__ float abar_s[64*32];
  int bid = blockIdx.x, tid = threadIdx.x;
  int g = bid & 1;                    // n-half: n in {3g,3g+1,3g+2}
  int bh = bid >> 1;                  // (bl,h) 0..511
  int h = bh & 3, bl = bh >> 2;
  const u16* qb = qh + (size_t)bh * 12288;
  const u16* kb = kh + (size_t)bh * 12288;
  const u16* vb = vh + (size_t)bh * 12288;

  int wave = tid >> 6, lane = tid & 63, lm = lane & 31, lh = lane >> 5;
  int n = g*3 + wave;

  // Q fragments: group A = q rows n*64+lm, group B = +32
  const u16* qbase = qb + (size_t)(n*64 + lm)*32 + lh*8;
  bf16x8 qfA0 = *(const bf16x8*)(qbase);
  bf16x8 qfA1 = *(const bf16x8*)(qbase + 16);
  bf16x8 qfB0 = *(const bf16x8*)(qbase + 32*32);
  bf16x8 qfB1 = *(const bf16x8*)(qbase + 32*32 + 16);

  // stage V transposed + key-swizzled: a-group perm {0,2,1,3,4,6,5,7}
  #pragma unroll
  for (int i = 0; i < 8; i++){
    int c = tid + i*192;               // 1536 16B chunks
    int key = c >> 2, part = c & 3;
    int u = key & 31, tt = key >> 5;
    int a = u >> 2;
    int anew = (a & 4) | ((a & 1) << 1) | ((a >> 1) & 1);
    int pos = tt*32 + anew*4 + (u & 3);
    u16x8 vv = *(const u16x8*)(vb + key*32 + part*8);
    #pragma unroll
    for (int jj = 0; jj < 8; jj++) vts[(part*8 + jj)*392 + pos] = vv[jj];
  }
  for (int idx = tid; idx < 2048; idx += 192) abar_s[idx] = 0.f;
  __syncthreads();

  const u16* vrow = &vts[lm*392 + 8*lh];
  const u16* krow = kb + lm*32 + lh*8;

  bf16x8 ones;
  #pragma unroll
  for (int j = 0; j < 8; j++) ones[j] = (__bf16)1.0f;

  f32x16 oA, oB, slA, slB;
  #pragma unroll
  for (int r = 0; r < 16; r++){ oA[r]=0.f; oB[r]=0.f; slA[r]=0.f; slB[r]=0.f; }

  #pragma unroll
  for (int kt = 0; kt < 12; kt++){
    bf16x8 kf0 = *(const bf16x8*)(krow + kt*1024);
    bf16x8 kf1 = *(const bf16x8*)(krow + kt*1024 + 16);
    f32x16 sa, sb_;
    #pragma unroll
    for (int r = 0; r < 16; r++){ sa[r] = 0.f; sb_[r] = 0.f; }
    __builtin_amdgcn_s_setprio(1);
    sa  = mfma_bf16(kf0, qfA0, sa);      // two independent chains (A/B)
    sb_ = mfma_bf16(kf0, qfB0, sb_);
    sa  = mfma_bf16(kf1, qfA1, sa);
    sb_ = mfma_bf16(kf1, qfB1, sb_);
    __builtin_amdgcn_s_setprio(0);
    U8 v0, v1;
    v0.u = *(const u16x8*)(vrow + kt*32);
    v1.u = *(const u16x8*)(vrow + kt*32 + 16);
    U8 pA0, pA1, pB0, pB1;
    #pragma unroll
    for (int r = 0; r < 8; r++){
      pA0.b[r] = (__bf16)EXP2(sa[r]);    // v_cvt_pk_bf16_f32 (RNE)
      pA1.b[r] = (__bf16)EXP2(sa[r+8]);
      pB0.b[r] = (__bf16)EXP2(sb_[r]);
      pB1.b[r] = (__bf16)EXP2(sb_[r+8]);
    }
    __builtin_amdgcn_s_setprio(1);
    oA  = mfma_bf16(pA0.b, v0.b, oA);
    oB  = mfma_bf16(pB0.b, v0.b, oB);
    slA = mfma_bf16(pA0.b, ones, slA);   // denominator rows align with O rows
    slB = mfma_bf16(pB0.b, ones, slB);
    oA  = mfma_bf16(pA1.b, v1.b, oA);
    oB  = mfma_bf16(pB1.b, v1.b, oB);
    slA = mfma_bf16(pA1.b, ones, slA);
    slB = mfma_bf16(pB1.b, ones, slB);
    __builtin_amdgcn_s_setprio(0);
  }

  // normalize elementwise (sl rows == o rows); 1/6 = mean over n folded in.
  #pragma unroll
  for (int r = 0; r < 16; r++){
    int q_l = (r&3) + 8*(r>>2) + 4*lh;
    float ia = (1.f/6.f) * __builtin_amdgcn_rcpf(slA[r]);
    float ib = (1.f/6.f) * __builtin_amdgcn_rcpf(slB[r]);
    atomicAdd(&abar_s[q_l*32 + lm], oA[r]*ia);
    atomicAdd(&abar_s[(32 + q_l)*32 + lm], oB[r]*ib);
  }
  __syncthreads();
  float* ob = (g ? abp1 : abp0) + (size_t)(bl*64)*128 + h*32;
  for (int idx = tid; idx < 2048; idx += 192){
    int w12 = idx >> 5, dh = idx & 31;
    ob[(size_t)w12*128 + dh] = abar_s[idx];
  }
}

// ---------------------------------------------------------------- k_out
// grid 256 = 8192 rows / 32; 256 thr (4 waves). Sums the two f32 partials,
// converts once to bf16 in LDS, then GEMM + skip.
__global__ __launch_bounds__(256) void k_out(
    const float* __restrict__ abp0, const float* __restrict__ abp1,
    const u16* __restrict__ wpT,
    const float* __restrict__ bp, const float* __restrict__ skip,
    float* __restrict__ out)
{
  __shared__ alignas(16) u16 Als[32*136];
  int tid = threadIdx.x;
  int R0 = blockIdx.x * 32;
  #pragma unroll
  for (int i = 0; i < 4; i++){
    int c = tid + i*256;                 // 1024 float4 chunks: 32 rows x 32
    int rw = c >> 5, part = c & 31;
    float4 a = ((const float4*)(abp0 + (size_t)(R0+rw)*128))[part];
    float4 b = ((const float4*)(abp1 + (size_t)(R0+rw)*128))[part];
    bf16x4 pk;
    pk[0] = (__bf16)(a.x + b.x); pk[1] = (__bf16)(a.y + b.y);
    pk[2] = (__bf16)(a.z + b.z); pk[3] = (__bf16)(a.w + b.w);
    *(bf16x4*)&Als[rw*136 + part*4] = pk;
  }
  __syncthreads();
  int wave = tid >> 6, lane = tid & 63, lm = lane & 31, lh = lane >> 5;
  bf16x8 bfr[8];
  const u16* wrow = wpT + (32*wave + lm)*128 + lh*8;
  #pragma unroll
  for (int ks = 0; ks < 8; ks++) bfr[ks] = *(const bf16x8*)(wrow + ks*16);
  f32x16 acc;
  #pragma unroll
  for (int r = 0; r < 16; r++) acc[r] = 0.f;
  #pragma unroll
  for (int ks = 0; ks < 8; ks++){
    bf16x8 a0 = *(const bf16x8*)&Als[lm*136 + ks*16 + lh*8];
    acc = mfma_bf16(a0, bfr[ks], acc);
  }
  float bias = bp[32*wave + lm];
  #pragma unroll
  for (int r = 0; r < 16; r++){
    int row0 = (r&3) + 8*(r>>2) + 4*lh;
    size_t f0 = (size_t)(R0 + row0)*128 + 32*wave + lm;
    out[f0] = acc[r] + bias + skip[f0];
  }
}

// ---------------------------------------------------------------- launch
extern "C" void kernel_launch(void* const* d_in, const int* in_sizes, int n_in,
                              void* d_out, int out_size, void* d_ws, size_t ws_size,
                              hipStream_t stream)
{
  const float* q    = (const float*)d_in[0];
  const float* k    = (const float*)d_in[1];
  const float* v    = (const float*)d_in[2];
  const float* skip = (const float*)d_in[3];
  const float* gq   = (const float*)d_in[4];
  const float* betq = (const float*)d_in[5];
  const float* gk   = (const float*)d_in[6];
  const float* betk = (const float*)d_in[7];
  const float* gv   = (const float*)d_in[8];
  const float* betv = (const float*)d_in[9];
  const float* wq   = (const float*)d_in[10];
  const float* bq   = (const float*)d_in[11];
  const float* wk   = (const float*)d_in[12];
  const float* bk   = (const float*)d_in[13];
  const float* wv   = (const float*)d_in[14];
  const float* bv   = (const float*)d_in[15];
  const float* wp   = (const float*)d_in[16];
  const float* bp   = (const float*)d_in[17];
  float* out = (float*)d_out;

  char* ws = (char*)d_ws;
  u16* wqT = (u16*)ws;                 // 16384 u16 each
  u16* wkT = wqT + 16384;
  u16* wvT = wkT + 16384;
  u16* wpT = wvT + 16384;
  float* bq2 = (float*)(ws + 131072);  // 128 f32 each
  float* bk2 = bq2 + 128;
  float* bv2 = bk2 + 128;
  float* uq2 = bv2 + 128;
  float* uk2 = uq2 + 128;
  float* uv2 = uk2 + 128;
  u16* qh = (u16*)(ws + 134144);       // [128][4][384][32] bf16 = 12.58 MB each
  u16* kh = qh + 6291456;
  u16* vh = kh + 6291456;
  float* abp0 = (float*)(ws + 37882880);   // [8192][128] f32 = 4 MB each
  float* abp1 = abp0 + 1048576;

  k_prep  <<<16,   512, 0, stream>>>(wq,bq,gq,betq, wk,bk,gk,betk, wv,bv,gv,betv, wp,
                                     wqT,wkT,wvT,wpT, bq2,bk2,bv2, uq2,uk2,uv2);
  k_lnproj<<<2304, 256, 0, stream>>>(q,k,v, wqT,wkT,wvT, bq2,bk2,bv2, uq2,uk2,uv2, qh,kh,vh);
  k_attn  <<<1024, 192, 0, stream>>>(qh,kh,vh, abp0,abp1);
  k_out   <<<256,  256, 0, stream>>>(abp0,abp1, wpT, bp, skip, out);
}

// Round 9
// 208.319 us; speedup vs baseline: 2.8953x; 1.0519x over previous
//
#include <hip/hip_runtime.h>

// CrossWinAttention on MI355X (gfx950), bf16 MFMA pipeline. R14 (resubmit;
// previous round was an infra failure, kernel never ran):
//  - k_attn: back to R7's exact best-measured body (48.1us: A/B dual chains,
//    serial sle sum — R11's ones-MFMA denominator measured +4-7us, reverted;
//    bf16 abar output) PLUS depth-12 K prefetch: all 24 K fragments (96 VGPR)
//    loaded upfront and pinned above the compute with sched_barrier(0).
//    Rationale: wall ~= FETCH/rate, rate scales with outstanding loads
//    (R8/R13: more concurrency -> 600-775 GB/s). R10's depth-1 prefetch was
//    too shallow (2 extra loads); 24 outstanding loads/wave is the full
//    footprint. VGPR ~150 < 170 cap for 2 blocks/CU x 6 waves.
//    R13's n-split reverted: it duplicated the K/V streams (FETCH 18.5->30.8).
//  - k_prep (grid 16), k_out (grid 256, bf16 abar): R11 versions.
//  - k_lnproj: R13b (LDS-staged coalesced u16x8 stores; measured-neutral).
//  - Carried: S^T trick, V^T key-swizzle, LN folded into GEMM epilogue,
//    mean-over-N folded, scale*log2e folded into wq/bq (exp2-only softmax),
//    hw bf16 cvt.

typedef unsigned short u16;
typedef __bf16 bf16x8 __attribute__((ext_vector_type(8)));
typedef __bf16 bf16x4 __attribute__((ext_vector_type(4)));
typedef float  f32x16 __attribute__((ext_vector_type(16)));
typedef unsigned short u16x8 __attribute__((ext_vector_type(8)));
typedef unsigned short u16x4 __attribute__((ext_vector_type(4)));

union U8 { u16x8 u; bf16x8 b; u16x4 h[2]; };

#if __has_builtin(__builtin_amdgcn_exp2f)
#define EXP2(x) __builtin_amdgcn_exp2f(x)
#else
#define EXP2(x) exp2f(x)
#endif

__device__ __forceinline__ f32x16 mfma_bf16(bf16x8 a, bf16x8 b, f32x16 c){
  return __builtin_amdgcn_mfma_f32_32x32x16_bf16(a, b, c, 0, 0, 0);
}

// 32x32x16 bf16 fragment conventions:
//  A: m=lane&31, k=(lane>>5)*8+j ; B: n=lane&31, k=(lane>>5)*8+j
//  C/D: col=lane&31, row=(reg&3)+8*(reg>>2)+4*(lane>>5)   [verified m74/m101]
// S^T = mfma(K, Q): col = q (fixed per lane), reg axis = keys; regs 0..7 are
// exactly the PV A-slots for keys 4lh+{0-3,8-11}, regs 8..15 for +16. V^T is
// stored with the matching key swizzle so PV B-fragments are single 16B reads.

// ---------------------------------------------------------------- k_prep
// grid 16 = 4 weights x 4 col-chunks; 512 thr.
__global__ __launch_bounds__(512) void k_prep(
    const float* __restrict__ wq, const float* __restrict__ bq,
    const float* __restrict__ gq, const float* __restrict__ betq,
    const float* __restrict__ wk, const float* __restrict__ bk,
    const float* __restrict__ gk, const float* __restrict__ betk,
    const float* __restrict__ wv, const float* __restrict__ bv,
    const float* __restrict__ gv, const float* __restrict__ betv,
    const float* __restrict__ wp,
    u16* __restrict__ wqT, u16* __restrict__ wkT, u16* __restrict__ wvT, u16* __restrict__ wpT,
    float* __restrict__ bq2, float* __restrict__ bk2, float* __restrict__ bv2,
    float* __restrict__ uq2, float* __restrict__ uk2, float* __restrict__ uv2)
{
  __shared__ float wls[128*33];
  __shared__ float gls[128], bls[128];
  __shared__ float redb[128], redu[128];
  const float ALPHA_Q = 0.17677669529663687f * 1.4426950408889634f; // DH^-0.5 * log2(e)
  int bid = blockIdx.x, tid = threadIdx.x;
  int wsel = bid >> 2, chunk = bid & 3;
  const float *w, *bb, *g, *bet; u16* wT; float *b2, *u2; float alpha;
  if (wsel == 0){ w=wq; bb=bq; g=gq; bet=betq; wT=wqT; b2=bq2; u2=uq2; alpha=ALPHA_Q; }
  else if (wsel == 1){ w=wk; bb=bk; g=gk; bet=betk; wT=wkT; b2=bk2; u2=uk2; alpha=1.f; }
  else if (wsel == 2){ w=wv; bb=bv; g=gv; bet=betv; wT=wvT; b2=bv2; u2=uv2; alpha=1.f; }
  else { w=wp; bb=nullptr; g=nullptr; bet=nullptr; wT=wpT; b2=nullptr; u2=nullptr; alpha=1.f; }

  if (tid < 128){
    gls[tid] = g ? g[tid] : 1.f;
    bls[tid] = bet ? bet[tid] : 0.f;
  }
  const float4* w4 = (const float4*)w;
  #pragma unroll
  for (int i = 0; i < 2; i++){
    int idx = tid + i*512;
    int row = idx >> 3, f4c = idx & 7;
    float4 x = w4[row*32 + chunk*8 + f4c];
    wls[row*33 + f4c*4 + 0] = x.x;
    wls[row*33 + f4c*4 + 1] = x.y;
    wls[row*33 + f4c*4 + 2] = x.z;
    wls[row*33 + f4c*4 + 3] = x.w;
  }
  __syncthreads();
  if (tid < 128){
    int nl = tid >> 2, qp = tid & 3;
    float sb = 0.f, su = 0.f;
    alignas(16) __bf16 tmp[32];
    #pragma unroll
    for (int kk = 0; kk < 32; kk++){
      int k2 = qp*32 + kk;
      float wv_ = wls[k2*33 + nl];
      float gv_ = gls[k2];
      sb += bls[k2] * wv_;
      su += gv_ * wv_;
      tmp[kk] = (__bf16)(wv_ * gv_ * alpha);
    }
    int n = chunk*32 + nl;
    #pragma unroll
    for (int j = 0; j < 4; j++)
      *(bf16x8*)(wT + n*128 + qp*32 + j*8) = *(bf16x8*)&tmp[j*8];
    redb[tid] = sb; redu[tid] = su;
  }
  __syncthreads();
  if (tid < 128){
    int nl = tid >> 2, qp = tid & 3;
    if (qp == 0 && bb){
      int n = chunk*32 + nl;
      float s = bb[n] + redb[tid] + redb[tid+1] + redb[tid+2] + redb[tid+3];
      float u = redu[tid] + redu[tid+1] + redu[tid+2] + redu[tid+3];
      b2[n] = s * alpha;
      u2[n] = u * alpha;
    }
  }
}

// ---------------------------------------------------------------- k_lnproj
// grid 2304 = 128 (b,l) * 6 (n) * 3 (q/k/v); 256 thr (4 waves).
// Raw-x bf16 GEMM; LN in epilogue; C staged via LDS for coalesced stores.
__global__ __launch_bounds__(256) void k_lnproj(
    const float* __restrict__ qg, const float* __restrict__ kg, const float* __restrict__ vg,
    const u16* __restrict__ wqT, const u16* __restrict__ wkT, const u16* __restrict__ wvT,
    const float* __restrict__ bq2, const float* __restrict__ bk2, const float* __restrict__ bv2,
    const float* __restrict__ uq2, const float* __restrict__ uk2, const float* __restrict__ uv2,
    u16* __restrict__ qh, u16* __restrict__ kh, u16* __restrict__ vh)
{
  __shared__ alignas(16) u16 Abf[64*136];
  __shared__ float s1s[64], s2s[64];     // rs / rm
  int bid = blockIdx.x, tid = threadIdx.x;
  int which = bid % 3;
  int t = bid / 3;
  int n = t % 6, bl = t / 6;
  const float* src; const u16* wT; const float *b2, *u2; u16* dstb;
  if (which == 0){ src=qg; wT=wqT; b2=bq2; u2=uq2; dstb=qh; }
  else if (which == 1){ src=kg; wT=wkT; b2=bk2; u2=uk2; dstb=kh; }
  else { src=vg; wT=wvT; b2=bv2; u2=uv2; dstb=vh; }
  int b = bl >> 6, l = bl & 63;
  const float4* s4 = (const float4*)(src + (size_t)((b*6 + n)*64 + l)*64*128);
  int row = tid >> 2, j = tid & 3;
  float s1 = 0.f, s2 = 0.f;
  #pragma unroll
  for (int i = 0; i < 8; i++){
    float4 xv = s4[row*32 + i*4 + j];
    s1 += xv.x + xv.y + xv.z + xv.w;
    s2 += xv.x*xv.x + xv.y*xv.y + xv.z*xv.z + xv.w*xv.w;
    bf16x4 pk;
    pk[0] = (__bf16)xv.x; pk[1] = (__bf16)xv.y;
    pk[2] = (__bf16)xv.z; pk[3] = (__bf16)xv.w;
    *(bf16x4*)&Abf[row*136 + (i*4 + j)*4] = pk;
  }
  s1 += __shfl_xor(s1, 1, 64); s1 += __shfl_xor(s1, 2, 64);
  s2 += __shfl_xor(s2, 1, 64); s2 += __shfl_xor(s2, 2, 64);
  if (j == 0){
    float m = s1 * (1.f/128.f);
    float r = rsqrtf(s2 * (1.f/128.f) - m*m + 1e-5f);
    s1s[row] = r;          // rs
    s2s[row] = r * m;      // rm
  }
  __syncthreads();
  int wave = tid >> 6, lane = tid & 63, lm = lane & 31, lh = lane >> 5;
  bf16x8 bfr[8];
  const u16* wrow = wT + (32*wave + lm)*128 + lh*8;
  #pragma unroll
  for (int ks = 0; ks < 8; ks++) bfr[ks] = *(const bf16x8*)(wrow + ks*16);
  f32x16 acc0, acc1;
  #pragma unroll
  for (int r = 0; r < 16; r++){ acc0[r]=0.f; acc1[r]=0.f; }
  #pragma unroll
  for (int ks = 0; ks < 8; ks++){
    bf16x8 a0 = *(const bf16x8*)&Abf[lm*136       + ks*16 + lh*8];
    bf16x8 a1 = *(const bf16x8*)&Abf[(32+lm)*136  + ks*16 + lh*8];
    acc0 = mfma_bf16(a0, bfr[ks], acc0);
    acc1 = mfma_bf16(a1, bfr[ks], acc1);
  }
  int col = 32*wave + lm;
  float u2c = u2[col], bc = b2[col];
  __syncthreads();                       // all waves done READING Abf
  #pragma unroll
  for (int r = 0; r < 16; r++){
    int row0 = (r&3) + 8*(r>>2) + 4*lh;
    float y0 = s1s[row0]     * acc0[r] - s2s[row0]     * u2c + bc;
    float y1 = s1s[row0+32]  * acc1[r] - s2s[row0+32]  * u2c + bc;
    *(__bf16*)&Abf[row0*136 + col]      = (__bf16)y0;
    *(__bf16*)&Abf[(32+row0)*136 + col] = (__bf16)y1;
  }
  __syncthreads();
  // coalesced store: 1024 u16x8 chunks = 4 colgroups x 64 rows x 4 parts
  #pragma unroll
  for (int i = 0; i < 4; i++){
    int c = tid + i*256;
    int grp = c >> 8, rw = (c >> 2) & 63, part = c & 3;
    u16x8 val = *(const u16x8*)&Abf[rw*136 + grp*32 + part*8];
    *(u16x8*)(dstb + ((size_t)(bl*4 + grp)*384 + n*64 + rw)*32 + part*8) = val;
  }
}

// ---------------------------------------------------------------- k_attn
// grid 512 = (b,l)*h; 384 thr = 6 waves; wave = n (owns all 64 q rows of its
// view: A = rows 0-31, B = rows 32-63). R7 body + depth-12 K prefetch: all
// 24 K fragments loaded upfront (96 VGPR), pinned by sched_barrier(0) ->
// 24 outstanding loads/wave instead of ~2 (the MLP lever R10's depth-1
// couldn't reach). V^T key-swizzled in LDS. LDS 34.3 KB, 2 blocks/CU.
__global__ __launch_bounds__(384) void k_attn(
    const u16* __restrict__ qh, const u16* __restrict__ kh, const u16* __restrict__ vh,
    u16* __restrict__ abar)
{
  __shared__ alignas(16) u16 vts[32*408];   // V^T [dh][swizzled key], stride 408
  __shared__ float abar_s[64*32];
  int bid = blockIdx.x, tid = threadIdx.x;
  int h = bid & 3, bl = bid >> 2;
  const u16* qb = qh + (size_t)bid * (384*32);
  const u16* kb = kh + (size_t)bid * (384*32);
  const u16* vb = vh + (size_t)bid * (384*32);

  int wave = tid >> 6, lane = tid & 63, lm = lane & 31, lh = lane >> 5;
  int n = wave;                       // 6 waves == 6 views

  // Q fragments: group A = q rows n*64+lm, group B = +32 (independent of LDS)
  const u16* qbase = qb + (size_t)(n*64 + lm)*32 + lh*8;
  bf16x8 qfA0 = *(const bf16x8*)(qbase);
  bf16x8 qfA1 = *(const bf16x8*)(qbase + 16);
  bf16x8 qfB0 = *(const bf16x8*)(qbase + 32*32);
  bf16x8 qfB1 = *(const bf16x8*)(qbase + 32*32 + 16);

  // depth-12 K prefetch: entire per-wave K footprint into registers (24x16B).
  const u16* krow = kb + lm*32 + lh*8;
  bf16x8 kfr[24];
  #pragma unroll
  for (int kt = 0; kt < 12; kt++){
    kfr[2*kt]   = *(const bf16x8*)(krow + kt*1024);
    kfr[2*kt+1] = *(const bf16x8*)(krow + kt*1024 + 16);
  }
  __builtin_amdgcn_sched_barrier(0);   // pin all K loads above the compute

  // stage V transposed + key-swizzled: key u (mod 32) at a-group perm{0,2,1,3,4,6,5,7}
  #pragma unroll
  for (int i = 0; i < 4; i++){
    int c = tid + i*384;               // 1536 16B chunks
    int key = c >> 2, part = c & 3;
    int u = key & 31, tt = key >> 5;
    int a = u >> 2;
    int anew = (a & 4) | ((a & 1) << 1) | ((a >> 1) & 1);
    int pos = tt*32 + anew*4 + (u & 3);
    u16x8 vv = *(const u16x8*)(vb + key*32 + part*8);
    #pragma unroll
    for (int jj = 0; jj < 8; jj++) vts[(part*8 + jj)*408 + pos] = vv[jj];
  }
  for (int idx = tid; idx < 2048; idx += 384) abar_s[idx] = 0.f;
  __syncthreads();

  const u16* vrow = &vts[lm*408 + 8*lh];

  f32x16 oA, oB;
  #pragma unroll
  for (int r = 0; r < 16; r++){ oA[r] = 0.f; oB[r] = 0.f; }
  float sleA = 0.f, sleB = 0.f;

  #pragma unroll
  for (int kt = 0; kt < 12; kt++){
    bf16x8 kf0 = kfr[2*kt];
    bf16x8 kf1 = kfr[2*kt+1];
    f32x16 sa, sb_;
    #pragma unroll
    for (int r = 0; r < 16; r++){ sa[r] = 0.f; sb_[r] = 0.f; }
    __builtin_amdgcn_s_setprio(1);
    sa  = mfma_bf16(kf0, qfA0, sa);      // two independent chains (A/B)
    sb_ = mfma_bf16(kf0, qfB0, sb_);
    sa  = mfma_bf16(kf1, qfA1, sa);
    sb_ = mfma_bf16(kf1, qfB1, sb_);
    __builtin_amdgcn_s_setprio(0);
    U8 v0, v1;
    v0.u = *(const u16x8*)(vrow + kt*32);
    v1.u = *(const u16x8*)(vrow + kt*32 + 16);
    U8 pA0, pA1, pB0, pB1;
    #pragma unroll
    for (int r = 0; r < 8; r++){
      float eA0 = EXP2(sa[r]);
      float eA1 = EXP2(sa[r+8]);
      float eB0 = EXP2(sb_[r]);
      float eB1 = EXP2(sb_[r+8]);
      sleA += eA0 + eA1;
      sleB += eB0 + eB1;
      pA0.b[r] = (__bf16)eA0;            // v_cvt_pk_bf16_f32 (RNE)
      pA1.b[r] = (__bf16)eA1;
      pB0.b[r] = (__bf16)eB0;
      pB1.b[r] = (__bf16)eB1;
    }
    __builtin_amdgcn_s_setprio(1);
    oA = mfma_bf16(pA0.b, v0.b, oA);
    oB = mfma_bf16(pB0.b, v0.b, oB);
    oA = mfma_bf16(pA1.b, v1.b, oA);
    oB = mfma_bf16(pB1.b, v1.b, oB);
    __builtin_amdgcn_s_setprio(0);
  }

  // row sums: combine lh halves, broadcast reciprocals (1/6 = mean over n)
  sleA += __shfl_xor(sleA, 32, 64);
  sleB += __shfl_xor(sleB, 32, 64);
  float invA = (1.f/6.f) / sleA;
  float invB = (1.f/6.f) / sleB;

  // o lane(lm,lh) reg r = O[q = (r&3)+8*(r>>2)+4*lh][dh = lm]; w12 = q (A), 32+q (B)
  #pragma unroll
  for (int r = 0; r < 16; r++){
    int q_l = (r&3) + 8*(r>>2) + 4*lh;
    float a = oA[r] * __shfl(invA, q_l, 64);
    float b = oB[r] * __shfl(invB, q_l, 64);
    atomicAdd(&abar_s[q_l*32 + lm], a);
    atomicAdd(&abar_s[(32 + q_l)*32 + lm], b);
  }
  __syncthreads();
  u16* ob = abar + (size_t)(bl*64)*128 + h*32;
  for (int idx = tid; idx < 2048; idx += 384){
    int w12 = idx >> 5, dh = idx & 31;
    *(__bf16*)&ob[(size_t)w12*128 + dh] = (__bf16)abar_s[idx];
  }
}

// ---------------------------------------------------------------- k_out
// grid 256 = 8192 rows / 32; 256 thr (4 waves); wave w owns cols [32w,32w+32).
__global__ __launch_bounds__(256) void k_out(
    const u16* __restrict__ abar, const u16* __restrict__ wpT,
    const float* __restrict__ bp, const float* __restrict__ skip,
    float* __restrict__ out)
{
  __shared__ alignas(16) u16 Als[32*136];
  int tid = threadIdx.x;
  int R0 = blockIdx.x * 32;
  #pragma unroll
  for (int i = 0; i < 2; i++){
    int c = tid + i*256;                 // 512 16B chunks: 32 rows x 16
    int row = c >> 4, part = c & 15;
    *(u16x8*)&Als[row*136 + part*8] = *(const u16x8*)(abar + (size_t)(R0+row)*128 + part*8);
  }
  __syncthreads();
  int wave = tid >> 6, lane = tid & 63, lm = lane & 31, lh = lane >> 5;
  bf16x8 bfr[8];
  const u16* wrow = wpT + (32*wave + lm)*128 + lh*8;
  #pragma unroll
  for (int ks = 0; ks < 8; ks++) bfr[ks] = *(const bf16x8*)(wrow + ks*16);
  f32x16 acc;
  #pragma unroll
  for (int r = 0; r < 16; r++) acc[r] = 0.f;
  #pragma unroll
  for (int ks = 0; ks < 8; ks++){
    bf16x8 a0 = *(const bf16x8*)&Als[lm*136 + ks*16 + lh*8];
    acc = mfma_bf16(a0, bfr[ks], acc);
  }
  float bias = bp[32*wave + lm];
  #pragma unroll
  for (int r = 0; r < 16; r++){
    int row0 = (r&3) + 8*(r>>2) + 4*lh;
    size_t f0 = (size_t)(R0 + row0)*128 + 32*wave + lm;
    out[f0] = acc[r] + bias + skip[f0];
  }
}

// ---------------------------------------------------------------- launch
extern "C" void kernel_launch(void* const* d_in, const int* in_sizes, int n_in,
                              void* d_out, int out_size, void* d_ws, size_t ws_size,
                              hipStream_t stream)
{
  const float* q    = (const float*)d_in[0];
  const float* k    = (const float*)d_in[1];
  const float* v    = (const float*)d_in[2];
  const float* skip = (const float*)d_in[3];
  const float* gq   = (const float*)d_in[4];
  const float* betq = (const float*)d_in[5];
  const float* gk   = (const float*)d_in[6];
  const float* betk = (const float*)d_in[7];
  const float* gv   = (const float*)d_in[8];
  const float* betv = (const float*)d_in[9];
  const float* wq   = (const float*)d_in[10];
  const float* bq   = (const float*)d_in[11];
  const float* wk   = (const float*)d_in[12];
  const float* bk   = (const float*)d_in[13];
  const float* wv   = (const float*)d_in[14];
  const float* bv   = (const float*)d_in[15];
  const float* wp   = (const float*)d_in[16];
  const float* bp   = (const float*)d_in[17];
  float* out = (float*)d_out;

  char* ws = (char*)d_ws;
  u16* wqT = (u16*)ws;                 // 16384 u16 each
  u16* wkT = wqT + 16384;
  u16* wvT = wkT + 16384;
  u16* wpT = wvT + 16384;
  float* bq2 = (float*)(ws + 131072);  // 128 f32 each
  float* bk2 = bq2 + 128;
  float* bv2 = bk2 + 128;
  float* uq2 = bv2 + 128;
  float* uk2 = uq2 + 128;
  float* uv2 = uk2 + 128;
  u16* qh = (u16*)(ws + 134144);       // [128][4][384][32] bf16 = 12.58 MB each
  u16* kh = qh + 6291456;
  u16* vh = kh + 6291456;
  u16* abar = vh + 6291456;            // [8192][128] bf16 = 2 MB

  k_prep  <<<16,   512, 0, stream>>>(wq,bq,gq,betq, wk,bk,gk,betk, wv,bv,gv,betv, wp,
                                     wqT,wkT,wvT,wpT, bq2,bk2,bv2, uq2,uk2,uv2);
  k_lnproj<<<2304, 256, 0, stream>>>(q,k,v, wqT,wkT,wvT, bq2,bk2,bv2, uq2,uk2,uv2, qh,kh,vh);
  k_attn  <<<512,  384, 0, stream>>>(qh,kh,vh, abar);
  k_out   <<<256,  256, 0, stream>>>(abar, wpT, bp, skip, out);
}